// Round 10
// baseline (407.453 us; speedup 1.0000x reference)
//
#include <hip/hip_runtime.h>

// out[b,s,j] = sum_k x[b,s,k] * w_concat[inv_perm[j], k] + bias[j]
// INT8 path: weights exact in i8; x per-token quantized (sx = absmax/127).
// Round 9: A-only LDS + B-from-global (fragment-packed, reg double-buffered).
// LDS read volume per K-tile drops 192KB -> 128KB; B operands are coalesced
// 1KB wave loads from a pre-packed layout, prefetched one tile ahead.

#define M_TOK 16384
#define N_O   4096
#define K_IN  4096
#define N8F   2048
#define NT    (K_IN / 128)   // 32 K-tiles of BK=128 i8 (128 B/row)

typedef __attribute__((ext_vector_type(4))) int i32x4;

__device__ __forceinline__ void gl_lds16(const void* g, void* l) {
  __builtin_amdgcn_global_load_lds(
      (const __attribute__((address_space(1))) unsigned int*)g,
      (__attribute__((address_space(3))) unsigned int*)l, 16, 0, 0);
}

__device__ __forceinline__ int clampq(float f) {
  int q = (int)rintf(f);
  return q > 127 ? 127 : (q < -127 ? -127 : q);
}

// ---- x prep: per-token absmax -> sx, quantize row-major xq (4096 B rows) ----
__global__ void prepx_kernel(const float* __restrict__ x,
                             float* __restrict__ sx, char* __restrict__ xq) {
  __shared__ float red[4];
  const int t = threadIdx.x;
  const int T = blockIdx.x;
  const float4* xr = (const float4*)(x + (size_t)T * K_IN);
  float4 v[4];
  float m = 0.f;
#pragma unroll
  for (int i = 0; i < 4; ++i) {
    v[i] = xr[t * 4 + i];
    m = fmaxf(m, fmaxf(fmaxf(fabsf(v[i].x), fabsf(v[i].y)),
                       fmaxf(fabsf(v[i].z), fabsf(v[i].w))));
  }
#pragma unroll
  for (int o = 32; o; o >>= 1) m = fmaxf(m, __shfl_xor(m, o));
  if ((t & 63) == 0) red[t >> 6] = m;
  __syncthreads();
  m = fmaxf(fmaxf(red[0], red[1]), fmaxf(red[2], red[3]));
  const float rq = m > 0.f ? 127.f / m : 0.f;
  if (t == 0) sx[T] = m * (1.f / 127.f);
  unsigned dw[4];
#pragma unroll
  for (int i = 0; i < 4; ++i) {
    int a0 = clampq(v[i].x * rq), a1 = clampq(v[i].y * rq);
    int a2 = clampq(v[i].z * rq), a3 = clampq(v[i].w * rq);
    dw[i] = (a0 & 255) | ((a1 & 255) << 8) | ((a2 & 255) << 16)
          | ((unsigned)(a3 & 255) << 24);
  }
  *(uint4*)(xq + (size_t)T * K_IN + t * 16) = make_uint4(dw[0], dw[1], dw[2], dw[3]);
}

// ---- pack W -> fragment-tiled global B layout (+ inv_perm + scale) ----
// col j -> bn=j>>8, wcq=(j>>6)&3, n=(j>>4)&3, lr=j&15.  chunk c (16B of k) ->
// kt=c>>3, kk=(c>>2)&1, lane=((c&3)<<4)|lr.
// addr = ((bn*32+kt)<<15) + wcq*8192 + kk*4096 + n*1024 + lane*16
__global__ void packb_kernel(const int4* __restrict__ q8, const float* __restrict__ s8,
                             const int4* __restrict__ q4, const float* __restrict__ s4,
                             const int* __restrict__ inv,
                             char* __restrict__ Bf, float* __restrict__ scale) {
  const int j = blockIdx.x;
  const int t = threadIdx.x;           // chunk c = t (0..255)
  const int c = inv[j];
  const int4* src; float s;
  if (c < N8F) { src = q8 + (size_t)c * (K_IN / 4);         s = s8[c]; }
  else         { src = q4 + (size_t)(c - N8F) * (K_IN / 4); s = s4[c - N8F]; }
  if (t == 0) scale[j] = s;
  unsigned dw[4];
#pragma unroll
  for (int i = 0; i < 4; ++i) {
    int4 v = src[t * 4 + i];
    dw[i] = (v.x & 255) | ((v.y & 255) << 8) | ((v.z & 255) << 16)
          | ((unsigned)(v.w & 255) << 24);
  }
  const int bn = j >> 8, wcq = (j >> 6) & 3, n = (j >> 4) & 3, lr = j & 15;
  const int kt = t >> 3, kk = (t >> 2) & 1, lane = ((t & 3) << 4) | lr;
  char* dst = Bf + (((size_t)bn * 32 + kt) << 15) + wcq * 8192 + kk * 4096 +
              n * 1024 + lane * 16;
  *(uint4*)dst = make_uint4(dw[0], dw[1], dw[2], dw[3]);
}

// ================= 256x256 i8 GEMM: A via LDS, B via global frags =================
// LDS (64 KiB): buf*32768 + half*16384 (A only, 256 rows x 128 B, st-swizzled)
#define TILEBODY(CUR, kt, BCUR, BNXT)                                                  \
  {                                                                                    \
    if ((kt) + 1 < NT) {                                                               \
      const int o = ((kt) + 1) << 7;                                                   \
      char* aD = aL0 + ((CUR) ^ 1) * 32768;                                            \
      gl_lds16(aG + o, aD);                                                            \
      gl_lds16(aG + 32768 + o, aD + 1024);                                             \
      gl_lds16(aG + 524288 + o, aD + 16384);                                           \
      gl_lds16(aG + 524288 + 32768 + o, aD + 17408);                                   \
      __builtin_amdgcn_sched_barrier(0);  /* pin: A-stage older than B loads */        \
      const char* bp = bBase + (size_t)((kt) + 1) * 32768;                             \
      _Pragma("unroll") for (int i = 0; i < 8; ++i)                                    \
        BNXT[i] = *(const i32x4*)(bp + ((i >> 2) << 12) + ((i & 3) << 10));            \
    }                                                                                  \
    const char* rA  = rA0 + (CUR) * 32768;                                             \
    const char* rAx = rA0x + (CUR) * 32768;                                            \
    i32x4 a0[4], a1[4];                                                                \
    _Pragma("unroll") for (int m_ = 0; m_ < 4; ++m_)                                   \
      a0[m_] = *(const i32x4*)(rA + m_ * 2048);                                        \
    _Pragma("unroll") for (int m_ = 0; m_ < 4; ++m_)                                   \
    _Pragma("unroll") for (int n_ = 0; n_ < 4; ++n_)                                   \
      acc[m_][n_] = __builtin_amdgcn_mfma_i32_16x16x64_i8(a0[m_], BCUR[n_],            \
                                                          acc[m_][n_], 0, 0, 0);       \
    _Pragma("unroll") for (int m_ = 0; m_ < 4; ++m_)                                   \
      a1[m_] = *(const i32x4*)(rAx + m_ * 2048);                                       \
    _Pragma("unroll") for (int m_ = 0; m_ < 4; ++m_)                                   \
    _Pragma("unroll") for (int n_ = 0; n_ < 4; ++n_)                                   \
      acc[m_][n_] = __builtin_amdgcn_mfma_i32_16x16x64_i8(a1[m_], BCUR[4 + n_],        \
                                                          acc[m_][n_], 0, 0, 0);       \
    _Pragma("unroll") for (int m_ = 0; m_ < 4; ++m_)                                   \
      a0[m_] = *(const i32x4*)(rA + (4 + m_) * 2048);                                  \
    _Pragma("unroll") for (int m_ = 0; m_ < 4; ++m_)                                   \
    _Pragma("unroll") for (int n_ = 0; n_ < 4; ++n_)                                   \
      acc[4 + m_][n_] = __builtin_amdgcn_mfma_i32_16x16x64_i8(a0[m_], BCUR[n_],        \
                                                              acc[4 + m_][n_], 0, 0, 0); \
    _Pragma("unroll") for (int m_ = 0; m_ < 4; ++m_)                                   \
      a1[m_] = *(const i32x4*)(rAx + (4 + m_) * 2048);                                 \
    _Pragma("unroll") for (int m_ = 0; m_ < 4; ++m_)                                   \
    _Pragma("unroll") for (int n_ = 0; n_ < 4; ++n_)                                   \
      acc[4 + m_][n_] = __builtin_amdgcn_mfma_i32_16x16x64_i8(a1[m_], BCUR[4 + n_],    \
                                                              acc[4 + m_][n_], 0, 0, 0); \
    if ((kt) + 1 < NT) {                                                               \
      asm volatile("s_waitcnt lgkmcnt(0)" ::: "memory");                               \
      asm volatile("s_waitcnt vmcnt(8)" ::: "memory");  /* drain A-stage(kt+1) */      \
      __builtin_amdgcn_sched_barrier(0);                                               \
      __builtin_amdgcn_s_barrier();                                                    \
    }                                                                                  \
  }

__global__ __launch_bounds__(512, 2)
void gemm_i8(const char* __restrict__ xq, const char* __restrict__ Bf,
             const float* __restrict__ sx, const float* __restrict__ scale,
             const float* __restrict__ bias, float* __restrict__ out) {
  __shared__ __align__(16) char sm[65536];
  const int t = threadIdx.x;
  const int w = t >> 6, l = t & 63;
  const int wr = w >> 2, wc = w & 3;          // 2M x 4N waves, 128x64 each
  // bijective XCD remap (nwg=1024): each XCD runs an 8bm x 4bn rectangle
  const int wg = blockIdx.x;
  const int xcd = wg & 7, local_ = wg >> 3;
  const int sub = local_ >> 5, pos = local_ & 31;
  const int bm = (xcd << 3) | (pos >> 2);
  const int bn = (sub << 2) | (pos & 3);
  const int row0 = bm * 256;

  // --- A staging: per-lane pre-swizzled global source (rule #21) ---
  const int srow = l >> 3;
  const int schunk = ((l & 7) ^ srow) * 16;
  const char* aG = xq + (size_t)(row0 + w * 16 + srow) * K_IN + schunk;
  char* aL0 = sm + w * 2048;                  // + buf*32768 + h*16384

  // --- A fragment-read bases (swizzled) ---
  const int lrow128 = (l & 15) * 128;
  const int cb0 = (((l >> 4) << 4) ^ ((l & 7) << 4));
  const char* rA0  = sm + wr * 16384 + lrow128 + cb0;
  const char* rA0x = sm + wr * 16384 + lrow128 + (cb0 ^ 64);

  // --- B fragment base (global, packed) ---
  const char* bBase = Bf + ((size_t)bn << 20) + wc * 8192 + l * 16;

  i32x4 acc[8][4];
#pragma unroll
  for (int m = 0; m < 8; ++m)
#pragma unroll
    for (int n = 0; n < 4; ++n) acc[m][n] = (i32x4){0, 0, 0, 0};

  i32x4 bP[8], bQ[8];

  // --- prologue: stage A(0) -> buf0; load B(0) -> bP; publish A ---
  gl_lds16(aG, aL0);
  gl_lds16(aG + 32768, aL0 + 1024);
  gl_lds16(aG + 524288, aL0 + 16384);
  gl_lds16(aG + 524288 + 32768, aL0 + 17408);
  __builtin_amdgcn_sched_barrier(0);
#pragma unroll
  for (int i = 0; i < 8; ++i)
    bP[i] = *(const i32x4*)(bBase + ((i >> 2) << 12) + ((i & 3) << 10));
  asm volatile("s_waitcnt vmcnt(8)" ::: "memory");   // A(0) done; B(0) in flight
  __builtin_amdgcn_sched_barrier(0);
  __builtin_amdgcn_s_barrier();

  for (int kt = 0; kt < NT; kt += 2) {
    TILEBODY(0, kt, bP, bQ);
    TILEBODY(1, kt + 1, bQ, bP);
  }

  // ---- epilogue: C/D col=lane&15, row=(lane>>4)*4+i ; out = acc*sx[r]*sc + bias
  const int orow0 = row0 + wr * 128 + ((l >> 4) << 2);
  const int ocol0 = bn * 256 + wc * 64 + (l & 15);
#pragma unroll
  for (int n = 0; n < 4; ++n) {
    const int col = ocol0 + n * 16;
    const float sc = scale[col];
    const float bi = bias[col];
#pragma unroll
    for (int m = 0; m < 8; ++m) {
      const int r = orow0 + m * 16;
      const float4 sxv = *(const float4*)(sx + r);
      out[(size_t)(r + 0) * N_O + col] = (float)acc[m][n][0] * (sxv.x * sc) + bi;
      out[(size_t)(r + 1) * N_O + col] = (float)acc[m][n][1] * (sxv.y * sc) + bi;
      out[(size_t)(r + 2) * N_O + col] = (float)acc[m][n][2] * (sxv.z * sc) + bi;
      out[(size_t)(r + 3) * N_O + col] = (float)acc[m][n][3] * (sxv.w * sc) + bi;
    }
  }
}

extern "C" void kernel_launch(void* const* d_in, const int* in_sizes, int n_in,
                              void* d_out, int out_size, void* d_ws, size_t ws_size,
                              hipStream_t stream) {
  const float* x    = (const float*)d_in[0];
  const int*   q8   = (const int*)d_in[1];
  const float* s8   = (const float*)d_in[2];
  const int*   q4   = (const int*)d_in[3];
  const float* s4   = (const float*)d_in[4];
  const int*   inv  = (const int*)d_in[5];
  const float* bias = (const float*)d_in[6];
  float* out = (float*)d_out;

  // ws layout: Bf (16 MiB) | scale (16 KiB) | sx (64 KiB) | xq (64 MiB)
  char* ws = (char*)d_ws;
  char*  Bf    = ws;
  float* scale = (float*)(ws + (size_t)N_O * K_IN);
  float* sx    = (float*)(ws + (size_t)N_O * K_IN + 65536);
  char*  xq    = ws + (size_t)N_O * K_IN + 65536 + 65536;

  prepx_kernel<<<M_TOK, 256, 0, stream>>>(x, sx, xq);
  packb_kernel<<<N_O, 256, 0, stream>>>((const int4*)q8, s8, (const int4*)q4, s4,
                                        inv, Bf, scale);
  gemm_i8<<<(M_TOK / 256) * (N_O / 256), 512, 0, stream>>>(xq, Bf, sx, scale,
                                                           bias, out);
}